// Round 12
// baseline (2290.316 us; speedup 1.0000x reference)
//
#include <hip/hip_runtime.h>
#include <hip/hip_bf16.h>
#include <stdint.h>

// Persistent-RNN, R16: R8's proven poll skeleton + R12's proven packed datapath.
//  - 128 blocks x 512 threads (8 waves). 8 batch-groups x 16 col-blocks.
//  - Block (g,m): g = blockIdx&7 (group==XCD, proven R8 x-dedup), m = blockIdx>>3.
//  - R14/R15 (2-deep ping-pong polling) failed to run twice: two asm-pinned
//    32-VGPR banks + 160 VGPR weights exceed the allocator's budget with tuple
//    constraints. Abandoned. R16 holds ONE bank (as every passing round).
//  - Poll = R8 exactly (kernel 1737): serial sweeps on the single tagged buffer,
//    alternating sc0 (cheap local check) / sc1 (LLC truth), late poll after
//    x-proj, fire-and-forget agent-scope store.
//  - Datapath = R12 exactly (passed, absmax 0.0039): state word (hi<<16)|lo is
//    bf16x2 [lo,hi] of ONE k; W[k] DUPLICATED in both B parity slots -> one
//    MFMA computes sum (s_lo+s_hi)*W. Zero unpack VALU; recurrent MFMAs 48->32,
//    x-proj 12->8. Sweep tiled so each loaded u32x4 IS an A-fragment verbatim:
//    lane (lr,lq) base dword = lr*128 + lq*4 (byte lr*512+lq*16), loads at
//    +0,64,...,448 B; sv_j is the A-fragment for kb=j>>1, p=j&1.
//  - Tag protocol: u32 = (bf16hi<<16)|(bf16lo&~1|parity); all 32 tags/lane must
//    equal (t>>1)&1; the passing sweep IS the state load; stale words carry the
//    opposite tag -> never false-pass; per-dword tags cover torn lines.
//  - WAR safety: as R5 -- fresh word from producer B implies B passed its
//    step-(t-1) barrier implies all its step-(t-1) reads retired (in regs).

#define TSTEPS 512
#define BATCH  128
#define NI     256
#define NH     1024
#define NO     128
#define NBLK   128
#define NTHR   512
#define NWAVE  8
#define BG     16
#define COLS   64

typedef __attribute__((ext_vector_type(8))) short s16x8;
typedef __attribute__((ext_vector_type(4))) float f32x4;
typedef __attribute__((ext_vector_type(4))) unsigned u32x4;
typedef unsigned long long ull;

__device__ __forceinline__ unsigned short f2bf_rne(float f) {
  unsigned u = __builtin_bit_cast(unsigned, f);
  unsigned r = u + 0x7fffu + ((u >> 16) & 1u);
  return (unsigned short)(r >> 16);
}
__device__ __forceinline__ float bf2f(unsigned short h) {
  unsigned u = ((unsigned)h) << 16;
  return __builtin_bit_cast(float, u);
}
__device__ __forceinline__ f32x4 mfma16(s16x8 a, s16x8 b, f32x4 c) {
  return __builtin_amdgcn_mfma_f32_16x16x32_bf16(a, b, c, 0, 0, 0);
}
__device__ __forceinline__ float fast_tanh(float a) {
  float cl = fminf(fmaxf(a, -15.f), 15.f);
  float e  = __expf(2.f * cl);
  return (e - 1.f) / (e + 1.f);
}
// pack float -> (bf16hi<<16)|bf16lo  (state-word orientation)
__device__ __forceinline__ unsigned packf(float v) {
  unsigned short h = f2bf_rne(v);
  unsigned short l = f2bf_rne(v - bf2f(h));
  return (((unsigned)h) << 16) | (unsigned)l;
}

// state u32 index: [g 0..8)[w 0..8)[r 0..16)[k_local 0..128)
#define SIDX(g, w, r, k) ((((size_t)(g) * NWAVE + (w)) * BG + (r)) * 128 + (k))

// one serial 8KB tagged sweep; sv_j IS A-fragment (kb=j>>1, p=j&1)
#define SWEEP(FLAG, PTR)                                                   \
  asm volatile(                                                            \
    "global_load_dwordx4 %0, %8, off " FLAG "\n\t"                         \
    "global_load_dwordx4 %1, %8, off offset:64 " FLAG "\n\t"               \
    "global_load_dwordx4 %2, %8, off offset:128 " FLAG "\n\t"              \
    "global_load_dwordx4 %3, %8, off offset:192 " FLAG "\n\t"              \
    "global_load_dwordx4 %4, %8, off offset:256 " FLAG "\n\t"              \
    "global_load_dwordx4 %5, %8, off offset:320 " FLAG "\n\t"              \
    "global_load_dwordx4 %6, %8, off offset:384 " FLAG "\n\t"              \
    "global_load_dwordx4 %7, %8, off offset:448 " FLAG "\n\t"              \
    "s_waitcnt vmcnt(0)"                                                   \
    : "=&v"(sv0), "=&v"(sv1), "=&v"(sv2), "=&v"(sv3),                      \
      "=&v"(sv4), "=&v"(sv5), "=&v"(sv6), "=&v"(sv7)                       \
    : "v"(PTR) : "memory")

#define TAGCHECK(OUT)                                                      \
  { u32x4 b4 = (sv0 ^ e4) | (sv1 ^ e4) | (sv2 ^ e4) | (sv3 ^ e4)           \
             | (sv4 ^ e4) | (sv5 ^ e4) | (sv6 ^ e4) | (sv7 ^ e4);          \
    OUT = (b4[0] | b4[1] | b4[2] | b4[3]) & 1u; }

__global__ __launch_bounds__(NTHR, 2)
void rnn_persistent(const float* __restrict__ x,
                    const float* __restrict__ W_ih,
                    const float* __restrict__ W_hh,
                    const float* __restrict__ b_ih,
                    const float* __restrict__ b_hh,
                    unsigned*    __restrict__ SP)    // [2][128][1024] tagged packed state
{
  const int tid  = threadIdx.x;
  const int wave = tid >> 6;
  const int lane = tid & 63;
  const int lr   = lane & 15;
  const int lq   = lane >> 4;
  const int g    = blockIdx.x & 7;     // group == chain == XCD (proven R8)
  const int m    = blockIdx.x >> 3;    // 16 col-blocks per group
  const int row0 = g * BG;
  const int h0   = m * COLS;
  const int kq0  = wave * 128;         // this wave's hidden-K slice
  const int iq0  = wave * 32;          // this wave's input-K slice

  __shared__ float red[2][NWAVE][1024];   // exactly 64 KiB

  // ---- persistent W_hh B-fragments, DUPLICATED-HI: [nt 0..3][kb 0..3][p 0..1] ----
  // element j = bf16(W_hh[h0+nt*16+lr][kq0 + kb*32 + p*16 + lq*4 + (j>>1)])
  s16x8 whhd[4][4][2];
  #pragma unroll
  for (int nt = 0; nt < 4; ++nt) {
    const int h = h0 + nt * 16 + lr;
    #pragma unroll
    for (int kb = 0; kb < 4; ++kb)
      #pragma unroll
      for (int p = 0; p < 2; ++p) {
        const float* pw = W_hh + (size_t)h * NH + kq0 + kb * 32 + p * 16 + lq * 4;
        s16x8 f;
        #pragma unroll
        for (int j = 0; j < 8; ++j) f[j] = (short)f2bf_rne(pw[j >> 1]);
        whhd[nt][kb][p] = f;
      }
  }
  // ---- persistent W_ih B-fragments, DUPLICATED-HI: [nt 0..3][p 0..1] ----
  s16x8 wihd[4][2];
  #pragma unroll
  for (int nt = 0; nt < 4; ++nt) {
    const int h = h0 + nt * 16 + lr;
    #pragma unroll
    for (int p = 0; p < 2; ++p) {
      const float* pw = W_ih + (size_t)h * NI + iq0 + p * 16 + lq * 4;
      s16x8 f;
      #pragma unroll
      for (int j = 0; j < 8; ++j) f[j] = (short)f2bf_rne(pw[j >> 1]);
      wihd[nt][p] = f;
    }
  }

  // epilogue ownership: thread -> row tid>>5, cols 2*(tid&31), +1
  const int er = tid >> 5;
  const int ec = (tid & 31) * 2;
  const float bias0 = b_ih[h0 + ec]     + b_hh[h0 + ec];
  const float bias1 = b_ih[h0 + ec + 1] + b_hh[h0 + ec + 1];
  const int wsl = m >> 1;              // wave-slice this block's cols land in
  const int klo = (m & 1) * 64 + ec;   // k_local of this thread's pair

  unsigned* buf0 = SP;
  unsigned* buf1 = SP + (size_t)BATCH * NH;

  // x fragments for step 0 (packed [lo,hi] dwords, fragment p = 0,1)
  s16x8 xfA, xfB;
  {
    const float* xp = x + (size_t)(row0 + lr) * NI + iq0 + lq * 4;
    f32x4 v0 = *(const f32x4*)xp;
    f32x4 v1 = *(const f32x4*)(xp + 16);
    u32x4 a, b;
    #pragma unroll
    for (int d = 0; d < 4; ++d) { a[d] = packf(v0[d]); b[d] = packf(v1[d]); }
    xfA = __builtin_bit_cast(s16x8, a);
    xfB = __builtin_bit_cast(s16x8, b);
  }

  // consumer poll base: lane's fragment-tiled offset within this wave's slice
  const unsigned* sb0 = buf0 + SIDX(g, wave, lr, lq * 4);
  const unsigned* sb1 = buf1 + SIDX(g, wave, lr, lq * 4);

  for (int t = 0; t < TSTEPS; ++t) {
    // ---------- x projection from prepacked fragments (8 MFMA) ----------
    f32x4 acc[4];
    #pragma unroll
    for (int nt = 0; nt < 4; ++nt) acc[nt] = (f32x4){0.f, 0.f, 0.f, 0.f};
    #pragma unroll
    for (int nt = 0; nt < 4; ++nt) {
      acc[nt] = mfma16(xfA, wihd[nt][0], acc[nt]);
      acc[nt] = mfma16(xfB, wihd[nt][1], acc[nt]);
    }
    // ---------- serial poll, R8 cadence: alternate sc0 (cheap) / sc1 (truth) ----------
    const unsigned etag = (unsigned)((t >> 1) & 1);
    const unsigned* sb = (t & 1) ? sb1 : sb0;
    u32x4 sv0, sv1, sv2, sv3, sv4, sv5, sv6, sv7;
    {
      const u32x4 e4 = (u32x4){etag, etag, etag, etag};
      unsigned bad;
      for (;;) {
        SWEEP("sc0", sb); TAGCHECK(bad); if (!bad) break;
        SWEEP("sc1", sb); TAGCHECK(bad); if (!bad) break;
      }
    }
    // ---------- issue x[t+1] prefetch (packs later, under the MFMAs) ----------
    f32x4 xv0, xv1;
    {
      const int tn = (t + 1 < TSTEPS) ? (t + 1) : t;
      const float* xp = x + (size_t)tn * BATCH * NI + (size_t)(row0 + lr) * NI + iq0 + lq * 4;
      xv0 = *(const f32x4*)xp;
      xv1 = *(const f32x4*)(xp + 16);
    }
    // ---------- recurrent MFMAs: packed fragments fed DIRECTLY (32 MFMA) ----------
    {
      const s16x8 a0 = __builtin_bit_cast(s16x8, sv0);
      const s16x8 a1 = __builtin_bit_cast(s16x8, sv1);
      const s16x8 a2 = __builtin_bit_cast(s16x8, sv2);
      const s16x8 a3 = __builtin_bit_cast(s16x8, sv3);
      const s16x8 a4 = __builtin_bit_cast(s16x8, sv4);
      const s16x8 a5 = __builtin_bit_cast(s16x8, sv5);
      const s16x8 a6 = __builtin_bit_cast(s16x8, sv6);
      const s16x8 a7 = __builtin_bit_cast(s16x8, sv7);
      #pragma unroll
      for (int nt = 0; nt < 4; ++nt) {
        acc[nt] = mfma16(a0, whhd[nt][0][0], acc[nt]);
        acc[nt] = mfma16(a1, whhd[nt][0][1], acc[nt]);
        acc[nt] = mfma16(a2, whhd[nt][1][0], acc[nt]);
        acc[nt] = mfma16(a3, whhd[nt][1][1], acc[nt]);
        acc[nt] = mfma16(a4, whhd[nt][2][0], acc[nt]);
        acc[nt] = mfma16(a5, whhd[nt][2][1], acc[nt]);
        acc[nt] = mfma16(a6, whhd[nt][3][0], acc[nt]);
        acc[nt] = mfma16(a7, whhd[nt][3][1], acc[nt]);
      }
    }
    // ---------- pack x[t+1] fragments (off the chain, loads already landed) ----------
    {
      u32x4 a, b;
      #pragma unroll
      for (int d = 0; d < 4; ++d) { a[d] = packf(xv0[d]); b[d] = packf(xv1[d]); }
      xfA = __builtin_bit_cast(s16x8, a);
      xfB = __builtin_bit_cast(s16x8, b);
    }
    // ---------- cross-wave K reduction (double-buffered -> ONE barrier/step) ----------
    // C/D layout: col = lane&15, row = quad*4 + reg (m89/m91 verified)
    const int rbi = t & 1;
    #pragma unroll
    for (int nt = 0; nt < 4; ++nt)
      #pragma unroll
      for (int r = 0; r < 4; ++r)
        red[rbi][wave][(lq * 4 + r) * 64 + nt * 16 + lr] = acc[nt][r];
    __syncthreads();
    // ---------- epilogue: reduce 8 waves, tanh, tagged store (fire, no drain) ----------
    {
      float s0 = bias0, s1 = bias1;
      #pragma unroll
      for (int w = 0; w < NWAVE; ++w) {
        float2 v = *(const float2*)&red[rbi][w][er * 64 + ec];
        s0 += v.x; s1 += v.y;
      }
      float t0 = fast_tanh(s0), t1 = fast_tanh(s1);
      const unsigned otag = (unsigned)(((t + 1) >> 1) & 1);
      unsigned short h0b = f2bf_rne(t0);
      unsigned       l0b = ((f2bf_rne(t0 - bf2f(h0b)) & 0xfffeu) | otag);
      unsigned short h1b = f2bf_rne(t1);
      unsigned       l1b = ((f2bf_rne(t1 - bf2f(h1b)) & 0xfffeu) | otag);
      ull pk = ((ull)(((unsigned)h1b << 16) | l1b) << 32)
             |  (ull)(((unsigned)h0b << 16) | l0b);
      ull* op = (ull*)(((t + 1) & 1 ? buf1 : buf0) + SIDX(g, wsl, er, klo));
      __hip_atomic_store(op, pk, __ATOMIC_RELAXED, __HIP_MEMORY_SCOPE_AGENT);
    }
  }
}

__global__ __launch_bounds__(256)
void init_buf1(unsigned* __restrict__ SP) {
  // buffer1 stale-tag init: consumers of s=1 expect tag 0 -> mark stale with LSB=1
  const int i = blockIdx.x * 256 + threadIdx.x;
  SP[BATCH * NH + i] = 1u;
}

__global__ __launch_bounds__(512)
void rnn_readout(const unsigned* __restrict__ SP,      // final state = buf0 (T even)
                 const float* __restrict__ W_ro,       // [128][1024]
                 const float* __restrict__ b_ro,       // [128]
                 float* __restrict__ out)              // [128][128]
{
  __shared__ float srow[4][NH];
  const int b0 = blockIdx.x * 4;
  for (int i = threadIdx.x; i < 4 * NH; i += 512) {
    const int b = b0 + (i >> 10);
    const int h = i & 1023;
    unsigned u = SP[SIDX(b >> 4, h >> 7, b & 15, h & 127)];
    srow[i >> 10][h] = bf2f((unsigned short)(u >> 16)) + bf2f((unsigned short)(u & 0xffffu));
  }
  __syncthreads();
  const int bb = threadIdx.x >> 7;
  const int o  = threadIdx.x & 127;
  const float* wr = W_ro + (size_t)o * NH;
  float s = 0.f;
  #pragma unroll 4
  for (int k = 0; k < NH; ++k) s += srow[bb][k] * wr[k];
  out[(size_t)(b0 + bb) * NO + o] = s + b_ro[o];
}

extern "C" void kernel_launch(void* const* d_in, const int* in_sizes, int n_in,
                              void* d_out, int out_size, void* d_ws, size_t ws_size,
                              hipStream_t stream) {
  (void)in_sizes; (void)n_in; (void)out_size; (void)ws_size;
  const float* x    = (const float*)d_in[0];
  const float* W_ih = (const float*)d_in[1];
  const float* W_hh = (const float*)d_in[2];
  const float* b_ih = (const float*)d_in[3];
  const float* b_hh = (const float*)d_in[4];
  const float* W_ro = (const float*)d_in[5];
  const float* b_ro = (const float*)d_in[6];
  float* out = (float*)d_out;

  unsigned* SP = (unsigned*)d_ws;   // [2][128][1024] u32 = 1 MB

  // buf0 = state s=0: zeros, tag LSB=0 -> plain memset
  hipMemsetAsync(SP, 0, (size_t)BATCH * NH * sizeof(unsigned), stream);
  // buf1 = stale marker (tag 1 != expected 0 for s=1)
  init_buf1<<<(BATCH * NH) / 256, 256, 0, stream>>>(SP);

  rnn_persistent<<<NBLK, NTHR, 0, stream>>>(x, W_ih, W_hh, b_ih, b_hh, SP);
  // T=512 even -> final state in buf0
  rnn_readout<<<BATCH / 4, 512, 0, stream>>>(SP, W_ro, b_ro, out);
}

// Round 13
// 1816.015 us; speedup vs baseline: 1.2612x; 1.2612x over previous
//
#include <hip/hip_runtime.h>
#include <hip/hip_bf16.h>
#include <stdint.h>

// Persistent-RNN, R17 == R10 (measured session-best, 1815.0 us total / ~1737 us kernel).
//  - 128 blocks x 512 threads (8 waves). 8 batch-groups x 16 col-blocks.
//  - Block (g,m): g = blockIdx&7 (group==XCD under round-robin dispatch -- proven
//    R8 FETCH dedup), m = blockIdx>>3.
//  - Final configuration after 12 regime probes (R5-R16). The plateau config:
//      * Producer stores tagged state TWICE: sc0 (SE scope -> this XCD's L2,
//        fast-path target) + sc1 (IC coherence point: liveness truth + readout
//        source). Fire-and-forget, no drain on the chain.
//      * Consumer: serial 8KB sweeps alternating sc0 (L2/L1 fast path, cheap
//        filler+backoff) / sc1 (mirror truth). Whichever sweep passes IS the
//        state load. 1:1 cadence measured optimal (1:0 funnels the XCD port:
//        R6/R12; 3:1/8:1 slow detection: R9; 2-deep pipelining: over VGPR
//        budget R14/R15; packed datapath: 3-for-3 regression R12/R13/R16 --
//        shorter compute phases phase-align concentrated pollers).
//  - Tag protocol: u32 = (bf16hi<<16)|(bf16lo&~1|parity); all 32 tags/lane must
//    equal (t>>1)&1; stale lines at any cache level carry the OPPOSITE tag ->
//    tag-fail, never false-pass; per-dword tags cover torn lines.
//  - WAR safety: fresh word from producer B implies B passed its step-(t-1)
//    block barrier implies all B's step-(t-1) state reads retired (in regs).
//  - Structural floor: 512 serial all-to-all exchanges x ~3.4us (store
//    visibility + LLC detect RT + 16-producer straggler max) with compute
//    (~0.5us/step) fully hidden under the poll; W_hh register-resident is
//    capacity-forced (streaming W would cost ~13us/step).

#define TSTEPS 512
#define BATCH  128
#define NI     256
#define NH     1024
#define NO     128
#define NBLK   128
#define NTHR   512
#define NWAVE  8
#define BG     16
#define COLS   64
#define SPBUF  ((size_t)BATCH * NH)          // u32s per state buffer (2^17)

typedef __attribute__((ext_vector_type(8))) short s16x8;
typedef __attribute__((ext_vector_type(4))) float f32x4;
typedef __attribute__((ext_vector_type(4))) unsigned u32x4;
typedef unsigned long long ull;

__device__ __forceinline__ unsigned short f2bf_rne(float f) {
  unsigned u = __builtin_bit_cast(unsigned, f);
  unsigned r = u + 0x7fffu + ((u >> 16) & 1u);
  return (unsigned short)(r >> 16);
}
__device__ __forceinline__ float bf2f(unsigned short h) {
  unsigned u = ((unsigned)h) << 16;
  return __builtin_bit_cast(float, u);
}
__device__ __forceinline__ void split_bf(float v, short &hi, short &lo) {
  unsigned short h = f2bf_rne(v);
  hi = (short)h;
  lo = (short)f2bf_rne(v - bf2f(h));
}
__device__ __forceinline__ f32x4 mfma16(s16x8 a, s16x8 b, f32x4 c) {
  return __builtin_amdgcn_mfma_f32_16x16x32_bf16(a, b, c, 0, 0, 0);
}
__device__ __forceinline__ float fast_tanh(float a) {
  float cl = fminf(fmaxf(a, -15.f), 15.f);
  float e  = __expf(2.f * cl);
  return (e - 1.f) / (e + 1.f);
}

// state u32 index: [g 0..8)[w 0..8)[r 0..16)[k_local 0..128)
//   global K = w*128 + k_local ; batch row = g*16 + r
#define SIDX(g, w, r, k) ((((size_t)(g) * NWAVE + (w)) * BG + (r)) * 128 + (k))

__global__ __launch_bounds__(NTHR, 2)
void rnn_persistent(const float* __restrict__ x,
                    const float* __restrict__ W_ih,
                    const float* __restrict__ W_hh,
                    const float* __restrict__ b_ih,
                    const float* __restrict__ b_hh,
                    unsigned*    __restrict__ SP)    // [4][128][1024]: L2buf0,L2buf1,MIR0,MIR1
{
  const int tid  = threadIdx.x;
  const int wave = tid >> 6;
  const int lane = tid & 63;
  const int lr   = lane & 15;
  const int lq   = lane >> 4;
  const int g    = blockIdx.x & 7;     // group == chain == XCD (round-robin, proven R8)
  const int m    = blockIdx.x >> 3;    // 16 col-blocks per group
  const int row0 = g * BG;
  const int h0   = m * COLS;
  const int kq0  = wave * 128;         // this wave's hidden-K slice
  const int iq0  = wave * 32;          // this wave's input-K slice

  __shared__ float red[2][NWAVE][1024];

  // ---- persistent W_hh B-fragments: [n-tile 0..3][kb 0..3], hi/lo ----
  s16x8 whh_hi[4][4], whh_lo[4][4];
  #pragma unroll
  for (int nt = 0; nt < 4; ++nt) {
    const int h = h0 + nt * 16 + lr;
    #pragma unroll
    for (int kb = 0; kb < 4; ++kb) {
      const float* p = W_hh + (size_t)h * NH + kq0 + kb * 32 + lq * 8;
      s16x8 hi, lo;
      #pragma unroll
      for (int j = 0; j < 8; ++j) { short a, b; split_bf(p[j], a, b); hi[j] = a; lo[j] = b; }
      whh_hi[nt][kb] = hi; whh_lo[nt][kb] = lo;
    }
  }
  // ---- persistent W_ih B-fragments: [n-tile 0..3], single 32-wide kb ----
  s16x8 wih_hi[4], wih_lo[4];
  #pragma unroll
  for (int nt = 0; nt < 4; ++nt) {
    const int h = h0 + nt * 16 + lr;
    const float* p = W_ih + (size_t)h * NI + iq0 + lq * 8;
    s16x8 hi, lo;
    #pragma unroll
    for (int j = 0; j < 8; ++j) { short a, b; split_bf(p[j], a, b); hi[j] = a; lo[j] = b; }
    wih_hi[nt] = hi; wih_lo[nt] = lo;
  }

  // epilogue ownership: thread -> row tid>>5, cols 2*(tid&31), +1
  const int er = tid >> 5;
  const int ec = (tid & 31) * 2;
  const float bias0 = b_ih[h0 + ec]     + b_hh[h0 + ec];
  const float bias1 = b_ih[h0 + ec + 1] + b_hh[h0 + ec + 1];
  const int wsl = m >> 1;              // wave-slice this block's cols land in
  const int klo = (m & 1) * 64 + ec;   // k_local of this thread's pair

  unsigned* lb0 = SP;                  // L2-scope double buffer
  unsigned* lb1 = SP + SPBUF;
  unsigned* mr0 = SP + 2 * SPBUF;      // IC mirror double buffer
  unsigned* mr1 = SP + 3 * SPBUF;

  // x prefetch registers (step 0)
  float xf[8];
  {
    const float* xp = x + (size_t)(row0 + lr) * NI + iq0 + lq * 8;
    #pragma unroll
    for (int j = 0; j < 8; ++j) xf[j] = xp[j];
  }

  // consumer poll bases: this wave's contiguous slice, per-lane fragment offset
  const size_t soff = SIDX(g, wave, lr, lq * 8);
  const unsigned* sbL[2] = { lb0 + soff, lb1 + soff };
  const unsigned* sbM[2] = { mr0 + soff, mr1 + soff };
  // producer store offset
  const size_t poff = SIDX(g, wsl, er, klo);

  for (int t = 0; t < TSTEPS; ++t) {
    // ---------- x projection from prefetched registers ----------
    f32x4 acc[4];
    #pragma unroll
    for (int nt = 0; nt < 4; ++nt) acc[nt] = (f32x4){0.f, 0.f, 0.f, 0.f};
    {
      s16x8 xhi, xlo;
      #pragma unroll
      for (int j = 0; j < 8; ++j) { short a, b; split_bf(xf[j], a, b); xhi[j] = a; xlo[j] = b; }
      #pragma unroll
      for (int nt = 0; nt < 4; ++nt) {
        acc[nt] = mfma16(xhi, wih_hi[nt], acc[nt]);
        acc[nt] = mfma16(xhi, wih_lo[nt], acc[nt]);
        acc[nt] = mfma16(xlo, wih_hi[nt], acc[nt]);
      }
    }
    // ---------- poll: alternate sc0 sweep (L2 fast path) / sc1 sweep (IC truth) ----------
    const unsigned etag = (unsigned)((t >> 1) & 1);
    const unsigned* sb = sbL[t & 1];
    const unsigned* mb = sbM[t & 1];
    u32x4 sv0, sv1, sv2, sv3, sv4, sv5, sv6, sv7;
    {
      const u32x4 e4 = (u32x4){etag, etag, etag, etag};
      for (;;) {
        // L2 fast path: sc0 (SE scope -> bypass L1, served by this XCD's L2)
        asm volatile(
          "global_load_dwordx4 %0, %8, off sc0\n\t"
          "global_load_dwordx4 %1, %8, off offset:16 sc0\n\t"
          "global_load_dwordx4 %2, %8, off offset:128 sc0\n\t"
          "global_load_dwordx4 %3, %8, off offset:144 sc0\n\t"
          "global_load_dwordx4 %4, %8, off offset:256 sc0\n\t"
          "global_load_dwordx4 %5, %8, off offset:272 sc0\n\t"
          "global_load_dwordx4 %6, %8, off offset:384 sc0\n\t"
          "global_load_dwordx4 %7, %8, off offset:400 sc0\n\t"
          "s_waitcnt vmcnt(0)"
          : "=&v"(sv0), "=&v"(sv1), "=&v"(sv2), "=&v"(sv3),
            "=&v"(sv4), "=&v"(sv5), "=&v"(sv6), "=&v"(sv7)
          : "v"(sb) : "memory");
        {
          u32x4 b4 = (sv0 ^ e4) | (sv1 ^ e4) | (sv2 ^ e4) | (sv3 ^ e4)
                   | (sv4 ^ e4) | (sv5 ^ e4) | (sv6 ^ e4) | (sv7 ^ e4);
          unsigned bad = b4[0] | b4[1] | b4[2] | b4[3];
          if ((bad & 1u) == 0) break;
        }
        // IC truth path (liveness regardless of placement/scope semantics)
        asm volatile(
          "global_load_dwordx4 %0, %8, off sc1\n\t"
          "global_load_dwordx4 %1, %8, off offset:16 sc1\n\t"
          "global_load_dwordx4 %2, %8, off offset:128 sc1\n\t"
          "global_load_dwordx4 %3, %8, off offset:144 sc1\n\t"
          "global_load_dwordx4 %4, %8, off offset:256 sc1\n\t"
          "global_load_dwordx4 %5, %8, off offset:272 sc1\n\t"
          "global_load_dwordx4 %6, %8, off offset:384 sc1\n\t"
          "global_load_dwordx4 %7, %8, off offset:400 sc1\n\t"
          "s_waitcnt vmcnt(0)"
          : "=&v"(sv0), "=&v"(sv1), "=&v"(sv2), "=&v"(sv3),
            "=&v"(sv4), "=&v"(sv5), "=&v"(sv6), "=&v"(sv7)
          : "v"(mb) : "memory");
        {
          u32x4 b4 = (sv0 ^ e4) | (sv1 ^ e4) | (sv2 ^ e4) | (sv3 ^ e4)
                   | (sv4 ^ e4) | (sv5 ^ e4) | (sv6 ^ e4) | (sv7 ^ e4);
          unsigned bad = b4[0] | b4[1] | b4[2] | b4[3];
          if ((bad & 1u) == 0) break;
        }
      }
    }
    // ---------- prefetch x[t+1] (hides HBM latency under MFMA + epilogue) ----------
    {
      const int tn = (t + 1 < TSTEPS) ? (t + 1) : t;
      const float* xp = x + (size_t)tn * BATCH * NI + (size_t)(row0 + lr) * NI + iq0 + lq * 8;
      #pragma unroll
      for (int j = 0; j < 8; ++j) xf[j] = xp[j];
    }
    // ---------- recurrent MFMAs (unpack + 3-product bf16x2) ----------
    {
      unsigned sw[32];
      #pragma unroll
      for (int e = 0; e < 4; ++e) {
        sw[0  + e] = sv0[e]; sw[4  + e] = sv1[e];
        sw[8  + e] = sv2[e]; sw[12 + e] = sv3[e];
        sw[16 + e] = sv4[e]; sw[20 + e] = sv5[e];
        sw[24 + e] = sv6[e]; sw[28 + e] = sv7[e];
      }
      #pragma unroll
      for (int kb = 0; kb < 4; ++kb) {
        s16x8 shi, slo;
        #pragma unroll
        for (int j = 0; j < 8; ++j) {
          unsigned w = sw[kb * 8 + j];
          shi[j] = (short)(w >> 16);
          slo[j] = (short)(w & 0xffffu);
        }
        #pragma unroll
        for (int nt = 0; nt < 4; ++nt) {
          acc[nt] = mfma16(shi, whh_hi[nt][kb], acc[nt]);
          acc[nt] = mfma16(shi, whh_lo[nt][kb], acc[nt]);
          acc[nt] = mfma16(slo, whh_hi[nt][kb], acc[nt]);
        }
      }
    }
    // ---------- cross-wave K reduction (double-buffered -> ONE barrier/step) ----------
    const int rbi = t & 1;
    #pragma unroll
    for (int nt = 0; nt < 4; ++nt)
      #pragma unroll
      for (int r = 0; r < 4; ++r)
        red[rbi][wave][(lq * 4 + r) * 64 + nt * 16 + lr] = acc[nt][r];
    __syncthreads();
    // ---------- epilogue: reduce 8 waves, tanh, dual tagged store (fire, no drain) ----------
    {
      float s0 = bias0, s1 = bias1;
      #pragma unroll
      for (int w = 0; w < NWAVE; ++w) {
        float2 v = *(const float2*)&red[rbi][w][er * 64 + ec];
        s0 += v.x; s1 += v.y;
      }
      float t0 = fast_tanh(s0), t1 = fast_tanh(s1);
      const unsigned otag = (unsigned)(((t + 1) >> 1) & 1);
      unsigned short h0b = f2bf_rne(t0);
      unsigned       l0b = ((f2bf_rne(t0 - bf2f(h0b)) & 0xfffeu) | otag);
      unsigned short h1b = f2bf_rne(t1);
      unsigned       l1b = ((f2bf_rne(t1 - bf2f(h1b)) & 0xfffeu) | otag);
      ull pk = ((ull)(((unsigned)h1b << 16) | l1b) << 32)
             |  (ull)(((unsigned)h0b << 16) | l0b);
      unsigned* lbd = ((t + 1) & 1) ? lb1 : lb0;
      unsigned* mrd = ((t + 1) & 1) ? mr1 : mr0;
      ull* opL = (ull*)(lbd + poff);
      ull* opM = (ull*)(mrd + poff);
      // (a) sc0 store -> SE scope: write-through past L1 into this XCD's L2
      asm volatile("global_store_dwordx2 %0, %1, off sc0" :: "v"(opL), "v"(pk) : "memory");
      // (b) sc1 store -> IC/HBM coherence point: liveness truth + readout source
      asm volatile("global_store_dwordx2 %0, %1, off sc1" :: "v"(opM), "v"(pk) : "memory");
    }
  }
}

__global__ __launch_bounds__(256)
void init_sp(unsigned* __restrict__ SP) {
  // regions: [0]=L2 buf0 (tag0 zeros), [1]=L2 buf1 (stale tag1),
  //          [2]=MIR buf0 (tag0 zeros), [3]=MIR buf1 (stale tag1)
  const size_t i = (size_t)blockIdx.x * 256 + threadIdx.x;
  SP[i] = (unsigned)((i >> 17) & 1);   // SPBUF = 2^17
}

__global__ __launch_bounds__(512)
void rnn_readout(const unsigned* __restrict__ SP,      // reads MIRROR buf0 (T even; sc1-visible)
                 const float* __restrict__ W_ro,       // [128][1024]
                 const float* __restrict__ b_ro,       // [128]
                 float* __restrict__ out)              // [128][128]
{
  __shared__ float srow[4][NH];
  const unsigned* MIR0 = SP + 2 * SPBUF;
  const int b0 = blockIdx.x * 4;
  for (int i = threadIdx.x; i < 4 * NH; i += 512) {
    const int b = b0 + (i >> 10);
    const int h = i & 1023;
    unsigned u = MIR0[SIDX(b >> 4, h >> 7, b & 15, h & 127)];
    srow[i >> 10][h] = bf2f((unsigned short)(u >> 16)) + bf2f((unsigned short)(u & 0xffffu));
  }
  __syncthreads();
  const int bb = threadIdx.x >> 7;
  const int o  = threadIdx.x & 127;
  const float* wr = W_ro + (size_t)o * NH;
  float s = 0.f;
  #pragma unroll 4
  for (int k = 0; k < NH; ++k) s += srow[bb][k] * wr[k];
  out[(size_t)(b0 + bb) * NO + o] = s + b_ro[o];
}

extern "C" void kernel_launch(void* const* d_in, const int* in_sizes, int n_in,
                              void* d_out, int out_size, void* d_ws, size_t ws_size,
                              hipStream_t stream) {
  (void)in_sizes; (void)n_in; (void)out_size; (void)ws_size;
  const float* x    = (const float*)d_in[0];
  const float* W_ih = (const float*)d_in[1];
  const float* W_hh = (const float*)d_in[2];
  const float* b_ih = (const float*)d_in[3];
  const float* b_hh = (const float*)d_in[4];
  const float* W_ro = (const float*)d_in[5];
  const float* b_ro = (const float*)d_in[6];
  float* out = (float*)d_out;

  unsigned* SP = (unsigned*)d_ws;   // [4][128][1024] u32 = 2 MB

  init_sp<<<(4 * BATCH * NH) / 256, 256, 0, stream>>>(SP);

  rnn_persistent<<<NBLK, NTHR, 0, stream>>>(x, W_ih, W_hh, b_ih, b_hh, SP);
  // T=512 even -> final state in buf0 (mirror copy, sc1-visible post-kernel)
  rnn_readout<<<BATCH / 4, 512, 0, stream>>>(SP, W_ro, b_ro, out);
}